// Round 6
// baseline (3001.044 us; speedup 1.0000x reference)
//
#include <hip/hip_runtime.h>

// Paired-block VRNN, v2. Pair = (bid, bid^4) on XCDs x / x+4, shared 32 rows.
// Gate GEMM N-split across pair -> per-XCD weight hot set 2.4MB (L2-resident).
// ONE exchange per step (h,c only): small layers P3-P5 duplicated on both
// members for all 32 rows. Flags padded to 256B (fix R4 false-sharing storm).
// eps/h_i/output streams use non-temporal hints to keep L2 for weights.

typedef __attribute__((ext_vector_type(8))) short short8;
typedef __attribute__((ext_vector_type(4))) float f32x4;
typedef unsigned long long u64;
typedef __attribute__((ext_vector_type(2))) unsigned long long u64x2;

#define Bt 4096
#define Td 16

// U layout (shorts): z@0, y_prev@64, h@320, s@832, y_cur@1344 ; stride 1608
#define US 1608
#define UZ 0
#define UY 64
#define UH 320
#define USs 832
#define UC 1344
#define TS 264
#define HZS 72

// weight ws offsets in short8 (16B) chunks
#define OFF_WGH  0          // 2 halves x 4 gates x NT16 x KT26
#define OFF_WPHH 212992     // 2 x 4 x NT16 x KT16
#define OFF_W1   344064     // NT16 KT16
#define OFF_W2   360448     // NT16 KT8
#define OFF_W3   368640
#define OFF_W4D  376832     // NT4 KT32  K=[s|y_cur|y_prev]
#define OFF_W4H  385024     // NT4 KT16
#define OFF_W7D  389120     // NT4 KT24  K=[s|y_prev]
#define OFF_W7H  395264
#define OFF_W5   399360     // NT4 KT2
#define OFF_W6   399872
#define OFF_W8   400384
#define OFF_W9   400896

// exchange: slot = (g*2+half)*2+par, 512 slots x 16KB each for XH and XC
#define XH_BYTE  6422528ULL
#define XC_BYTE  (XH_BYTE + 512ULL*16384)
#define FL_BYTE  (XC_BYTE + 512ULL*16384)
#define FPAD 64   // ints per flag slot (256B) — avoid false sharing

#define O1 16777216
#define O2 20971520
#define O3 25165824

__device__ inline short f2bf(float f) {
  unsigned u = __builtin_bit_cast(unsigned, f);
  unsigned r = (u + 0x7FFFu + ((u >> 16) & 1u)) >> 16;
  return (short)(unsigned short)r;
}
__device__ inline float sigm(float x) { return 1.f / (1.f + __expf(-x)); }
__device__ inline float tanhx(float x) { return 1.f - 2.f / (__expf(2.f * x) + 1.f); }
__device__ inline unsigned pack2(float a, float b) {
  return (unsigned)(unsigned short)f2bf(a) | ((unsigned)(unsigned short)f2bf(b) << 16);
}
__device__ inline f32x4 unpack4(unsigned u0, unsigned u1) {
  f32x4 r;
  r[0] = __builtin_bit_cast(float, u0 << 16);
  r[1] = __builtin_bit_cast(float, u0 & 0xffff0000u);
  r[2] = __builtin_bit_cast(float, u1 << 16);
  r[3] = __builtin_bit_cast(float, u1 & 0xffff0000u);
  return r;
}

#define MFMA(a, b, c) __builtin_amdgcn_mfma_f32_16x16x32_bf16((a), (b), (c), 0, 0, 0)

// f32 row-major [K][N] (up to 3 concatenated row-ranges) -> bf16 MFMA frag
__global__ void conv_frag(const float* s0, int k0, const float* s1, int k1,
                          const float* s2, int k2, int N, int col0,
                          short8* dst, int KT, int total) {
  int idx = blockIdx.x * blockDim.x + threadIdx.x;
  if (idx >= total) return;
  int lane = idx & 63;
  int tt = idx >> 6;
  int kt = tt % KT;
  int nt = tt / KT;
  int c = col0 + nt * 16 + (lane & 15);
  int kb = kt * 32 + (lane >> 4) * 8;
  short8 v;
#pragma unroll
  for (int j = 0; j < 8; ++j) {
    int kc = kb + j;
    float f;
    if (kc < k0) f = s0[(size_t)kc * N + c];
    else if (kc < k0 + k1) f = s1[(size_t)(kc - k0) * N + c];
    else f = s2[(size_t)(kc - k0 - k1) * N + c];
    v[j] = f2bf(f);
  }
  dst[idx] = v;
}

__global__ void init_flags(int* f) {
  int i = blockIdx.x * blockDim.x + threadIdx.x;
  if (i < 256 * FPAD) f[i] = 0;
}

struct Params {
  const float* h_i; const float* eps_inf; const float* eps_pri;
  const float* b_lstm;
  const float *b1, *b2, *b3, *b4, *b5, *b6, *b7, *b8, *b9;
  const short8 *WGH, *WPHH, *W1f, *W2f, *W3f, *W4D, *W4H, *W7D, *W7H,
               *W5f, *W6f, *W8f, *W9f;
  u64 *XH, *XC;
  int* flags;
  float* out;
};

__global__ __launch_bounds__(1024, 1) void vrnn_kernel(Params p) {
  __shared__ short U[32 * US];
  __shared__ short T1[32 * TS];
  __shared__ short T2[32 * TS];

  const int tid = threadIdx.x;
  const int wv = tid >> 6;
  const int lane = tid & 63;
  const int lrow = lane >> 4;
  const int lcol = lane & 15;
  const int bid = blockIdx.x;
  const int xcd = bid & 7;
  const int half = xcd >> 2;
  const int g = (xcd & 3) * 32 + (bid >> 3);
  const int rowbase = g * 32;
  const int ownrow0 = half * 16;
  const int fown = (g * 2 + half) * FPAD;
  const int fpar = (g * 2 + (1 - half)) * FPAD;
  // P4/P5 wave mapping
  const int net = wv >> 3;          // 0=inference, 1=prior
  const int rt = (wv >> 2) & 1;     // row tile
  const int q = wv & 3;             // N tile (Z=64 -> 4 tiles)

  // ---- stage h_i into U.h (NT loads) ----
  for (int i = tid; i < 32 * 512; i += 1024) {
    int r = i >> 9, c = i & 511;
    U[r * US + UH + c] =
        f2bf(__builtin_nontemporal_load(&p.h_i[(size_t)(rowbase + r) * 512 + c]));
  }
  __syncthreads();

  // ---- base = h_i @ WxH + b_lstm (per wave: 2 rowtiles x 4 gates, packed) ----
  unsigned base_pk[2][4][2];
  {
    const short8* Wb = p.WPHH + (size_t)(half * 4) * 16 * 16 * 64;
    f32x4 a2[2][4];
#pragma unroll
    for (int G = 0; G < 4; ++G) {
      float b = p.b_lstm[G * 512 + half * 256 + wv * 16 + lcol];
      a2[0][G] = (f32x4){b, b, b, b};
      a2[1][G] = (f32x4){b, b, b, b};
    }
    for (int kt = 0; kt < 16; ++kt) {
      short8 a0 = *(const short8*)&U[lcol * US + UH + kt * 32 + lrow * 8];
      short8 a1 = *(const short8*)&U[(16 + lcol) * US + UH + kt * 32 + lrow * 8];
#pragma unroll
      for (int G = 0; G < 4; ++G) {
        short8 w = Wb[(size_t)((G * 16 + wv) * 16 + kt) * 64 + lane];
        a2[0][G] = MFMA(a0, w, a2[0][G]);
        a2[1][G] = MFMA(a1, w, a2[1][G]);
      }
    }
#pragma unroll
    for (int rh = 0; rh < 2; ++rh)
#pragma unroll
      for (int G = 0; G < 4; ++G) {
        base_pk[rh][G][0] = pack2(a2[rh][G][0], a2[rh][G][1]);
        base_pk[rh][G][1] = pack2(a2[rh][G][2], a2[rh][G][3]);
      }
  }
  // ---- base47: wave (net, rt, q) ----
  f32x4 base47;
  {
    const short8* W = net ? p.W7H : p.W4H;
    const float* bb = net ? p.b7 : p.b4;
    float b = bb[q * 16 + lcol];
    base47 = (f32x4){b, b, b, b};
    for (int kt = 0; kt < 16; ++kt) {
      short8 a = *(const short8*)&U[(rt * 16 + lcol) * US + UH + kt * 32 + lrow * 8];
      short8 w = W[(q * 16 + kt) * 64 + lane];
      base47 = MFMA(a, w, base47);
    }
  }
  __syncthreads();
  // zero dynamic U region (cols 0..1600, all 32 rows) — initial states are 0
  for (int i = tid; i < 6400; i += 1024) {
    int r = i / 200, c8 = i % 200;
    *(short8*)&U[r * US + c8 * 8] = (short8){0, 0, 0, 0, 0, 0, 0, 0};
  }
  f32x4 cst[2];
  cst[0] = (f32x4){0.f, 0.f, 0.f, 0.f};
  cst[1] = (f32x4){0.f, 0.f, 0.f, 0.f};
  __syncthreads();

  // ---- time loop ----
  for (int t = 0; t < Td; ++t) {
    const int par = t & 1;
    // P1: gates (N-half, 32 rows), depth-1 weight prefetch
    f32x4 acc[2][4];
#pragma unroll
    for (int rh = 0; rh < 2; ++rh)
#pragma unroll
      for (int G = 0; G < 4; ++G)
        acc[rh][G] = unpack4(base_pk[rh][G][0], base_pk[rh][G][1]);
    {
      const short8* Wg = p.WGH + (size_t)(half * 4) * 16 * 26 * 64;
      short8 w[4], wn[4];
#pragma unroll
      for (int G = 0; G < 4; ++G)
        w[G] = Wg[(size_t)((G * 16 + wv) * 26) * 64 + lane];
      for (int kt = 0; kt < 26; ++kt) {
        short8 a0 = *(const short8*)&U[lcol * US + kt * 32 + lrow * 8];
        short8 a1 = *(const short8*)&U[(16 + lcol) * US + kt * 32 + lrow * 8];
        if (kt < 25) {
#pragma unroll
          for (int G = 0; G < 4; ++G)
            wn[G] = Wg[(size_t)((G * 16 + wv) * 26 + kt + 1) * 64 + lane];
        }
#pragma unroll
        for (int G = 0; G < 4; ++G) {
          acc[0][G] = MFMA(a0, w[G], acc[0][G]);
          acc[1][G] = MFMA(a1, w[G], acc[1][G]);
        }
#pragma unroll
        for (int G = 0; G < 4; ++G) w[G] = wn[G];
      }
    }
    __syncthreads();

    // P2: LSTM pointwise (own cols, all 32 rows)
    {
      int hc = half * 256 + wv * 16 + lcol;
#pragma unroll
      for (int rh = 0; rh < 2; ++rh)
#pragma unroll
        for (int r = 0; r < 4; ++r) {
          float iv = sigm(acc[rh][0][r]);
          float fv = sigm(acc[rh][1][r]);
          float gv = tanhx(acc[rh][2][r]);
          float ov = sigm(acc[rh][3][r]);
          float cn = fv * cst[rh][r] + iv * gv;
          cst[rh][r] = cn;
          float hn = ov * tanhx(cn);
          int row = rh * 16 + lrow * 4 + r;
          U[row * US + UH + hc] = f2bf(hn);
          U[row * US + USs + hc] = f2bf(cn);
        }
    }
    __syncthreads();
    // E1 write: own h,c col-halves (32 rows) -> XH,XC
    {
      u64* xh = p.XH + (size_t)((g * 2 + half) * 2 + par) * 2048;
      u64* xc = p.XC + (size_t)((g * 2 + half) * 2 + par) * 2048;
      int row = tid >> 5, c8 = tid & 31;
      short8 hv = *(const short8*)&U[row * US + UH + half * 256 + c8 * 8];
      short8 cv = *(const short8*)&U[row * US + USs + half * 256 + c8 * 8];
      u64x2 h2 = __builtin_bit_cast(u64x2, hv);
      u64x2 c2 = __builtin_bit_cast(u64x2, cv);
      __hip_atomic_store(&xh[tid * 2 + 0], h2[0], __ATOMIC_RELAXED, __HIP_MEMORY_SCOPE_AGENT);
      __hip_atomic_store(&xh[tid * 2 + 1], h2[1], __ATOMIC_RELAXED, __HIP_MEMORY_SCOPE_AGENT);
      __hip_atomic_store(&xc[tid * 2 + 0], c2[0], __ATOMIC_RELAXED, __HIP_MEMORY_SCOPE_AGENT);
      __hip_atomic_store(&xc[tid * 2 + 1], c2[1], __ATOMIC_RELAXED, __HIP_MEMORY_SCOPE_AGENT);
    }
    __syncthreads();
    if (tid == 0) {
      __hip_atomic_fetch_add(&p.flags[fown], 1, __ATOMIC_RELEASE, __HIP_MEMORY_SCOPE_AGENT);
      while (__hip_atomic_load(&p.flags[fpar], __ATOMIC_ACQUIRE, __HIP_MEMORY_SCOPE_AGENT) < t + 1)
        __builtin_amdgcn_s_sleep(2);
    }
    __syncthreads();
    // E1 read: partner h,c -> other col-half of U
    {
      u64* xh = p.XH + (size_t)((g * 2 + (1 - half)) * 2 + par) * 2048;
      u64* xc = p.XC + (size_t)((g * 2 + (1 - half)) * 2 + par) * 2048;
      int row = tid >> 5, c8 = tid & 31;
      u64x2 h2, c2;
      h2[0] = __hip_atomic_load(&xh[tid * 2 + 0], __ATOMIC_RELAXED, __HIP_MEMORY_SCOPE_AGENT);
      h2[1] = __hip_atomic_load(&xh[tid * 2 + 1], __ATOMIC_RELAXED, __HIP_MEMORY_SCOPE_AGENT);
      c2[0] = __hip_atomic_load(&xc[tid * 2 + 0], __ATOMIC_RELAXED, __HIP_MEMORY_SCOPE_AGENT);
      c2[1] = __hip_atomic_load(&xc[tid * 2 + 1], __ATOMIC_RELAXED, __HIP_MEMORY_SCOPE_AGENT);
      *(short8*)&U[row * US + UH + (1 - half) * 256 + c8 * 8] = __builtin_bit_cast(short8, h2);
      *(short8*)&U[row * US + USs + (1 - half) * 256 + c8 * 8] = __builtin_bit_cast(short8, c2);
    }
    __syncthreads();

    // P3: y-MLP for ALL 32 rows (weights read once, reused across row tiles)
    {
      float b = p.b1[wv * 16 + lcol];
      f32x4 o0 = (f32x4){b, b, b, b}, o1 = o0;
      for (int kt = 0; kt < 16; ++kt) {
        short8 a0 = *(const short8*)&U[lcol * US + UH + kt * 32 + lrow * 8];
        short8 a1 = *(const short8*)&U[(16 + lcol) * US + UH + kt * 32 + lrow * 8];
        short8 w = p.W1f[(wv * 16 + kt) * 64 + lane];
        o0 = MFMA(a0, w, o0);
        o1 = MFMA(a1, w, o1);
      }
#pragma unroll
      for (int r = 0; r < 4; ++r) {
        T1[(lrow * 4 + r) * TS + wv * 16 + lcol] = f2bf(fmaxf(o0[r], 0.f));
        T1[(16 + lrow * 4 + r) * TS + wv * 16 + lcol] = f2bf(fmaxf(o1[r], 0.f));
      }
    }
    __syncthreads();
    {
      float b = p.b2[wv * 16 + lcol];
      f32x4 o0 = (f32x4){b, b, b, b}, o1 = o0;
      for (int kt = 0; kt < 8; ++kt) {
        short8 a0 = *(const short8*)&T1[lcol * TS + kt * 32 + lrow * 8];
        short8 a1 = *(const short8*)&T1[(16 + lcol) * TS + kt * 32 + lrow * 8];
        short8 w = p.W2f[(wv * 8 + kt) * 64 + lane];
        o0 = MFMA(a0, w, o0);
        o1 = MFMA(a1, w, o1);
      }
#pragma unroll
      for (int r = 0; r < 4; ++r) {
        T2[(lrow * 4 + r) * TS + wv * 16 + lcol] = f2bf(fmaxf(o0[r], 0.f));
        T2[(16 + lrow * 4 + r) * TS + wv * 16 + lcol] = f2bf(fmaxf(o1[r], 0.f));
      }
    }
    __syncthreads();
    {
      float b = p.b3[wv * 16 + lcol];
      f32x4 o0 = (f32x4){b, b, b, b}, o1 = o0;
      for (int kt = 0; kt < 8; ++kt) {
        short8 a0 = *(const short8*)&T2[lcol * TS + kt * 32 + lrow * 8];
        short8 a1 = *(const short8*)&T2[(16 + lcol) * TS + kt * 32 + lrow * 8];
        short8 w = p.W3f[(wv * 8 + kt) * 64 + lane];
        o0 = MFMA(a0, w, o0);
        o1 = MFMA(a1, w, o1);
      }
#pragma unroll
      for (int r = 0; r < 4; ++r) {
        int crow = lrow * 4 + r;
        float v0 = fmaxf(o0[r], 0.f), v1 = fmaxf(o1[r], 0.f);
        U[crow * US + UC + wv * 16 + lcol] = f2bf(v0);
        U[(16 + crow) * US + UC + wv * 16 + lcol] = f2bf(v1);
        float vh = half ? v1 : v0;   // own rows only -> HBM (NT)
        __builtin_nontemporal_store(
            vh, &p.out[(size_t)(rowbase + ownrow0 + crow) * 4096 + t * 256 + wv * 16 + lcol]);
      }
    }
    __syncthreads();

    // P4: h_z — wave (net, rt, q), rows rt*16..+16
    {
      f32x4 hz = base47;
      const int arow = rt * 16 + lcol;
      if (net == 0) {
        for (int kt = 0; kt < 32; ++kt) {
          int kk = kt < 16 ? USs + 32 * kt : (kt < 24 ? UC + 32 * (kt - 16) : UY + 32 * (kt - 24));
          short8 a = *(const short8*)&U[arow * US + kk + lrow * 8];
          hz = MFMA(a, p.W4D[(q * 32 + kt) * 64 + lane], hz);
        }
#pragma unroll
        for (int r = 0; r < 4; ++r)
          T1[(rt * 16 + lrow * 4 + r) * HZS + q * 16 + lcol] = f2bf(fmaxf(hz[r], 0.f));
      } else {
        for (int kt = 0; kt < 24; ++kt) {
          int kk = kt < 16 ? USs + 32 * kt : UY + 32 * (kt - 16);
          short8 a = *(const short8*)&U[arow * US + kk + lrow * 8];
          hz = MFMA(a, p.W7D[(q * 24 + kt) * 64 + lane], hz);
        }
#pragma unroll
        for (int r = 0; r < 4; ++r)
          T2[(rt * 16 + lrow * 4 + r) * HZS + q * 16 + lcol] = f2bf(fmaxf(hz[r], 0.f));
      }
    }
    __syncthreads();

    // P5: heads + sampling — wave (net, rt, q)
    {
      const short8* Wm = net ? p.W8f : p.W5f;
      const short8* Wl = net ? p.W9f : p.W6f;
      const float* bm = net ? p.b8 : p.b5;
      const float* bl = net ? p.b9 : p.b6;
      const short* HZ = net ? T2 : T1;
      float b0 = bm[q * 16 + lcol], b1v = bl[q * 16 + lcol];
      f32x4 om = (f32x4){b0, b0, b0, b0};
      f32x4 ol = (f32x4){b1v, b1v, b1v, b1v};
#pragma unroll
      for (int kt = 0; kt < 2; ++kt) {
        short8 a = *(const short8*)&HZ[(rt * 16 + lcol) * HZS + kt * 32 + lrow * 8];
        om = MFMA(a, Wm[(q * 2 + kt) * 64 + lane], om);
        ol = MFMA(a, Wl[(q * 2 + kt) * 64 + lane], ol);
      }
      if (net == 0) {
#pragma unroll
        for (int r = 0; r < 4; ++r) {
          int crow = rt * 16 + lrow * 4 + r;
          int grow = rowbase + crow;
          int col = q * 16 + lcol;
          float mv = fmaxf(om[r], 0.f), lv = fmaxf(ol[r], 0.f);
          float ev = __builtin_nontemporal_load(&p.eps_inf[((size_t)t * Bt + grow) * 64 + col]);
          float zv = mv + ev * sqrtf(__expf(lv));
          U[crow * US + UZ + col] = f2bf(zv);   // z state, all 32 rows
          if (rt == half) {
            size_t gb = (size_t)grow * 1024 + t * 64 + col;
            __builtin_nontemporal_store(mv, &p.out[O1 + gb]);
            __builtin_nontemporal_store(lv, &p.out[O2 + gb]);
            __builtin_nontemporal_store(zv, &p.out[O3 + ((size_t)(t * 2 + 0) * Bt + grow) * 64 + col]);
          }
        }
      } else if (rt == half) {
#pragma unroll
        for (int r = 0; r < 4; ++r) {
          int crow = rt * 16 + lrow * 4 + r;
          int grow = rowbase + crow;
          int col = q * 16 + lcol;
          float mv = fmaxf(om[r], 0.f), lv = fmaxf(ol[r], 0.f);
          float ev = __builtin_nontemporal_load(&p.eps_pri[((size_t)t * Bt + grow) * 64 + col]);
          float zv = mv + ev * sqrtf(__expf(lv));
          __builtin_nontemporal_store(zv, &p.out[O3 + ((size_t)(t * 2 + 1) * Bt + grow) * 64 + col]);
        }
      }
    }
    __syncthreads();

    // P6: y_cur -> y_prev (all 32 rows, local)
    {
      int row = tid >> 5, c8 = tid & 31;
      short8 v = *(const short8*)&U[row * US + UC + c8 * 8];
      *(short8*)&U[row * US + UY + c8 * 8] = v;
    }
    __syncthreads();
  }
}

extern "C" void kernel_launch(void* const* d_in, const int* in_sizes, int n_in,
                              void* d_out, int out_size, void* d_ws, size_t ws_size,
                              hipStream_t stream) {
  const float* h_i     = (const float*)d_in[0];
  const float* eps_inf = (const float*)d_in[1];
  const float* eps_pri = (const float*)d_in[2];
  const float* Wx      = (const float*)d_in[3];
  const float* Wh      = (const float*)d_in[4];
  const float* b_lstm  = (const float*)d_in[5];
  const float* W1 = (const float*)d_in[6];  const float* b1 = (const float*)d_in[7];
  const float* W2 = (const float*)d_in[8];  const float* b2 = (const float*)d_in[9];
  const float* W3 = (const float*)d_in[10]; const float* b3 = (const float*)d_in[11];
  const float* W4 = (const float*)d_in[12]; const float* b4 = (const float*)d_in[13];
  const float* W5 = (const float*)d_in[14]; const float* b5 = (const float*)d_in[15];
  const float* W6 = (const float*)d_in[16]; const float* b6 = (const float*)d_in[17];
  const float* W7 = (const float*)d_in[18]; const float* b7 = (const float*)d_in[19];
  const float* W8 = (const float*)d_in[20]; const float* b8 = (const float*)d_in[21];
  const float* W9 = (const float*)d_in[22]; const float* b9 = (const float*)d_in[23];
  short8* ws = (short8*)d_ws;
  char* wsb = (char*)d_ws;
  const float* nil = nullptr;

  auto cv = [&](const float* s0, int k0, const float* s1, int k1,
                const float* s2, int k2, int N, int col0, int off, int KT, int NT) {
    int total = NT * KT * 64;
    conv_frag<<<(total + 255) / 256, 256, 0, stream>>>(s0, k0, s1, k1, s2, k2,
                                                       N, col0, ws + off, KT, total);
  };
  for (int half = 0; half < 2; ++half)
    for (int G = 0; G < 4; ++G) {
      int col0 = G * 512 + half * 256;
      cv(Wx, 64, Wx + 576 * 2048, 256, Wh, 512, 2048, col0,
         OFF_WGH + (half * 4 + G) * 16 * 26 * 64, 26, 16);
      cv(Wx + 64 * 2048, 512, nil, 0, nil, 0, 2048, col0,
         OFF_WPHH + (half * 4 + G) * 16 * 16 * 64, 16, 16);
    }
  cv(W1, 512, nil, 0, nil, 0, 256, 0, OFF_W1, 16, 16);
  cv(W2, 256, nil, 0, nil, 0, 256, 0, OFF_W2, 8, 16);
  cv(W3, 256, nil, 0, nil, 0, 256, 0, OFF_W3, 8, 16);
  cv(W4 + 512 * 64, 512, W4 + 1024 * 64, 256, W4 + 1280 * 64, 256, 64, 0, OFF_W4D, 32, 4);
  cv(W4, 512, nil, 0, nil, 0, 64, 0, OFF_W4H, 16, 4);
  cv(W7 + 512 * 64, 512, W7 + 1024 * 64, 256, nil, 0, 64, 0, OFF_W7D, 24, 4);
  cv(W7, 512, nil, 0, nil, 0, 64, 0, OFF_W7H, 16, 4);
  cv(W5, 64, nil, 0, nil, 0, 64, 0, OFF_W5, 2, 4);
  cv(W6, 64, nil, 0, nil, 0, 64, 0, OFF_W6, 2, 4);
  cv(W8, 64, nil, 0, nil, 0, 64, 0, OFF_W8, 2, 4);
  cv(W9, 64, nil, 0, nil, 0, 64, 0, OFF_W9, 2, 4);

  int* flags = (int*)(wsb + FL_BYTE);
  init_flags<<<(256 * FPAD + 255) / 256, 256, 0, stream>>>(flags);

  static Params P;
  P = Params{h_i, eps_inf, eps_pri, b_lstm,
             b1, b2, b3, b4, b5, b6, b7, b8, b9,
             ws + OFF_WGH, ws + OFF_WPHH, ws + OFF_W1, ws + OFF_W2, ws + OFF_W3,
             ws + OFF_W4D, ws + OFF_W4H, ws + OFF_W7D, ws + OFF_W7H,
             ws + OFF_W5, ws + OFF_W6, ws + OFF_W8, ws + OFF_W9,
             (u64*)(wsb + XH_BYTE), (u64*)(wsb + XC_BYTE),
             flags, (float*)d_out};
  void* args[] = {&P};
  hipLaunchCooperativeKernel((void*)vrnn_kernel, dim3(256), dim3(1024), args, 0, stream);
}

// Round 7
// 2083.898 us; speedup vs baseline: 1.4401x; 1.4401x over previous
//
#include <hip/hip_runtime.h>

// Persistent-block VRNN (R2 structure: 16 rows/block, 16 waves, no cross-block
// sync). R7 change: ALL global streams except the big gate-weight array WG are
// non-temporal (nt) -> L2 per XCD holds only WG (3.41MB < 4MB) -> WG becomes
// L2-resident across all 16 timesteps instead of thrashing to LLC.

typedef __attribute__((ext_vector_type(8))) short short8;
typedef __attribute__((ext_vector_type(4))) float f32x4;

#define Bt 4096
#define Hd 512
#define Fd 256
#define Zd 64
#define Td 16

// workspace offsets in short8 (16B) chunks
#define OFF_WG   0          // gates dyn: K=832 ([z|y_prev|h]), N=2048, KT=26, NT=128
#define OFF_WPH  212992     // h_i gates: K=512, N=2048, KT=16
#define OFF_W1   344064     // K=512 N=256 KT=16 NT=16
#define OFF_W2   360448     // K=256 N=256 KT=8
#define OFF_W3   368640
#define OFF_W4D  376832     // K=1024 ([s|y_prev|y_cur]) N=64 KT=32 NT=4
#define OFF_W4H  385024     // K=512 N=64 KT=16
#define OFF_W7D  389120     // K=768 ([s|y_prev]) N=64 KT=24
#define OFF_W7H  395264     // K=512 N=64 KT=16
#define OFF_W5   399360     // K=64 N=64 KT=2
#define OFF_W6   399872
#define OFF_W8   400384
#define OFF_W9   400896

#define O1 16777216   // mean_all offset in floats
#define O2 20971520   // log_var_all
#define O3 25165824   // z_all

__device__ inline short f2bf(float f) {
  unsigned u = __builtin_bit_cast(unsigned, f);
  unsigned r = (u + 0x7FFFu + ((u >> 16) & 1u)) >> 16;
  return (short)(unsigned short)r;
}
__device__ inline float sigm(float x) { return 1.f / (1.f + __expf(-x)); }
__device__ inline float tanhx(float x) { return 1.f - 2.f / (__expf(2.f * x) + 1.f); }

// Convert f32 weights (row-major [K][N], up to 3 concatenated row-ranges) into
// bf16 MFMA fragment order.
__global__ void conv_frag(const float* s0, int k0, const float* s1, int k1,
                          const float* s2, int k2, int N, short8* dst, int KT,
                          int total) {
  int idx = blockIdx.x * blockDim.x + threadIdx.x;
  if (idx >= total) return;
  int lane = idx & 63;
  int tt = idx >> 6;
  int kt = tt % KT;
  int nt = tt / KT;
  int c = nt * 16 + (lane & 15);
  int kb = kt * 32 + (lane >> 4) * 8;
  short8 v;
#pragma unroll
  for (int j = 0; j < 8; ++j) {
    int kc = kb + j;
    float f;
    if (kc < k0) f = s0[kc * N + c];
    else if (kc < k0 + k1) f = s1[(kc - k0) * N + c];
    else f = s2[(kc - k0 - k1) * N + c];
    v[j] = f2bf(f);
  }
  dst[idx] = v;
}

struct Params {
  const float* h_i; const float* eps_inf; const float* eps_pri;
  const float* b_lstm;
  const float *b1, *b2, *b3, *b4, *b5, *b6, *b7, *b8, *b9;
  const short8 *WG, *WPH, *W1f, *W2f, *W3f, *W4d, *W4h, *W7d, *W7h,
               *W5f, *W6f, *W8f, *W9f;
  float* out;
};

#define A1S 840    // [z(0:64)|y_prev(64:320)|h(320:832)] +8 pad
#define A4S 1032   // [s(0:512)|y_prev(512:768)|y_cur(768:1024)] +8 pad
#define TS  264
#define HZS 72

#define MFMA(a, b, c) __builtin_amdgcn_mfma_f32_16x16x32_bf16((a), (b), (c), 0, 0, 0)

// single-output-tile dense: out tile nt, K = KT*32 from LDS A. Weights NT.
template <int KT>
__device__ inline f32x4 dense1(const short* Asrc, int astride, int aoff,
                               const short8* W, const float* bias,
                               int nt, int lane) {
  int lrow = lane >> 4, lcol = lane & 15;
  float b = bias[nt * 16 + lcol];
  f32x4 o = (f32x4){b, b, b, b};
  for (int kt = 0; kt < KT; ++kt) {
    short8 a = *(const short8*)&Asrc[lcol * astride + aoff + kt * 32 + lrow * 8];
    short8 w = __builtin_nontemporal_load(&W[(nt * KT + kt) * 64 + lane]);
    o = MFMA(a, w, o);
  }
  return o;
}

__global__ __launch_bounds__(1024, 1) void vrnn_kernel(Params p) {
  __shared__ short A1[16 * A1S];
  __shared__ short A4[16 * A4S];
  __shared__ short T1[16 * TS];
  __shared__ short T2[16 * TS];
  __shared__ short HZi[16 * HZS];
  __shared__ short HZp[16 * HZS];
  __shared__ float Mi[1024], Li[1024], Mp[1024], Lp[1024];

  const int tid = threadIdx.x;
  const int wave = tid >> 6;
  const int lane = tid & 63;
  const int lrow = lane >> 4;
  const int lcol = lane & 15;
  const int rowbase = blockIdx.x * 16;

  f32x4 base[4][2];   // [gate][j] per-wave gate base (h_i@Wx + b_lstm)
  f32x4 cst[2];       // cell state fragments
  f32x4 base47 = (f32x4){0.f, 0.f, 0.f, 0.f};

  // ---- init: stage h_i (bf16) into A1.h, zero dynamic slots ----
  for (int i = tid; i < 16 * 512; i += 1024) {
    int r = i >> 9, c = i & 511;
    A1[r * A1S + 320 + c] =
        f2bf(__builtin_nontemporal_load(&p.h_i[(rowbase + r) * Hd + c]));
  }
  for (int i = tid; i < 16 * 320; i += 1024) {
    int r = i / 320, c = i - r * 320;
    A1[r * A1S + c] = 0;
  }
  for (int i = tid; i < 16 * 256; i += 1024) {
    int r = i >> 8, c = i & 255;
    A4[r * A4S + 512 + c] = 0;
  }
  __syncthreads();

  // ---- precompute base = h_i @ Wx_h + b_lstm (WPH read once -> NT) ----
#pragma unroll
  for (int g = 0; g < 4; ++g)
#pragma unroll
    for (int j = 0; j < 2; ++j) {
      float b = p.b_lstm[g * 512 + wave * 32 + j * 16 + lcol];
      base[g][j] = (f32x4){b, b, b, b};
    }
  for (int kt = 0; kt < 16; ++kt) {
    short8 a = *(const short8*)&A1[lcol * A1S + 320 + kt * 32 + lrow * 8];
#pragma unroll
    for (int g = 0; g < 4; ++g)
#pragma unroll
      for (int j = 0; j < 2; ++j) {
        int nt = g * 32 + wave * 2 + j;
        short8 w = __builtin_nontemporal_load(&p.WPH[(nt * 16 + kt) * 64 + lane]);
        base[g][j] = MFMA(a, w, base[g][j]);
      }
  }
  // ---- precompute base4 / base7 (waves 0-7) ----
  if (wave < 8) {
    const short8* W = (wave < 4) ? p.W4h : p.W7h;
    const float* bb = (wave < 4) ? p.b4 : p.b7;
    int nt = wave & 3;
    float b = bb[nt * 16 + lcol];
    base47 = (f32x4){b, b, b, b};
    for (int kt = 0; kt < 16; ++kt) {
      short8 a = *(const short8*)&A1[lcol * A1S + 320 + kt * 32 + lrow * 8];
      short8 w = __builtin_nontemporal_load(&W[(nt * 16 + kt) * 64 + lane]);
      base47 = MFMA(a, w, base47);
    }
  }
  __syncthreads();
  // zero h (initial LSTM state)
  for (int i = tid; i < 16 * 512; i += 1024) {
    int r = i >> 9, c = i & 511;
    A1[r * A1S + 320 + c] = 0;
  }
#pragma unroll
  for (int j = 0; j < 2; ++j) cst[j] = (f32x4){0.f, 0.f, 0.f, 0.f};
  __syncthreads();

  // ---- time loop ----
  for (int t = 0; t < Td; ++t) {
    // phase 1: gates = [z|y_prev|h] @ WG + base  (WG = the L2-resident set,
    // NORMAL loads on purpose)
    f32x4 acc[4][2];
#pragma unroll
    for (int g = 0; g < 4; ++g)
#pragma unroll
      for (int j = 0; j < 2; ++j) acc[g][j] = base[g][j];
#pragma unroll 2
    for (int kt = 0; kt < 26; ++kt) {
      short8 a = *(const short8*)&A1[lcol * A1S + kt * 32 + lrow * 8];
#pragma unroll
      for (int g = 0; g < 4; ++g)
#pragma unroll
        for (int j = 0; j < 2; ++j) {
          int nt = g * 32 + wave * 2 + j;
          short8 w = p.WG[(nt * 26 + kt) * 64 + lane];
          acc[g][j] = MFMA(a, w, acc[g][j]);
        }
    }
    __syncthreads();

    // phase 2: LSTM pointwise; write h_new -> A1.h, c_new -> A4.s
#pragma unroll
    for (int j = 0; j < 2; ++j) {
#pragma unroll
      for (int r = 0; r < 4; ++r) {
        float iv = sigm(acc[0][j][r]);
        float fv = sigm(acc[1][j][r]);
        float gv = tanhx(acc[2][j][r]);
        float ov = sigm(acc[3][j][r]);
        float cn = fv * cst[j][r] + iv * gv;
        cst[j][r] = cn;
        float hn = ov * tanhx(cn);
        int row = lrow * 4 + r;
        int col = wave * 32 + j * 16 + lcol;
        A1[row * A1S + 320 + col] = f2bf(hn);
        A4[row * A4S + col] = f2bf(cn);
      }
    }
    __syncthreads();

    // phase 3: y = relu(relu(relu(h@W1)@W2)@W3)   (1 out tile / wave, NT W)
    {
      f32x4 o = dense1<16>(A1, A1S, 320, p.W1f, p.b1, wave, lane);
#pragma unroll
      for (int r = 0; r < 4; ++r)
        T1[(lrow * 4 + r) * TS + wave * 16 + lcol] = f2bf(fmaxf(o[r], 0.f));
    }
    __syncthreads();
    {
      f32x4 o = dense1<8>(T1, TS, 0, p.W2f, p.b2, wave, lane);
#pragma unroll
      for (int r = 0; r < 4; ++r)
        T2[(lrow * 4 + r) * TS + wave * 16 + lcol] = f2bf(fmaxf(o[r], 0.f));
    }
    __syncthreads();
    {
      f32x4 o = dense1<8>(T2, TS, 0, p.W3f, p.b3, wave, lane);
#pragma unroll
      for (int r = 0; r < 4; ++r) {
        int row = lrow * 4 + r;
        int col = wave * 16 + lcol;
        float v = fmaxf(o[r], 0.f);
        A4[row * A4S + 768 + col] = f2bf(v);
        __builtin_nontemporal_store(
            v, &p.out[(size_t)(rowbase + row) * 4096 + t * 256 + col]);
      }
    }
    __syncthreads();

    // phase 4: h_z (inf, waves 0-3, K=1024) / h_z_ (pri, waves 4-7, K=768)
    if (wave < 8) {
      f32x4 hz = base47;
      if (wave < 4) {
        int nt = wave;
        for (int kt = 0; kt < 32; ++kt) {
          short8 a = *(const short8*)&A4[lcol * A4S + kt * 32 + lrow * 8];
          short8 w = __builtin_nontemporal_load(&p.W4d[(nt * 32 + kt) * 64 + lane]);
          hz = MFMA(a, w, hz);
        }
#pragma unroll
        for (int r = 0; r < 4; ++r)
          HZi[(lrow * 4 + r) * HZS + nt * 16 + lcol] = f2bf(fmaxf(hz[r], 0.f));
      } else {
        int nt = wave - 4;
        for (int kt = 0; kt < 24; ++kt) {
          short8 a = *(const short8*)&A4[lcol * A4S + kt * 32 + lrow * 8];
          short8 w = __builtin_nontemporal_load(&p.W7d[(nt * 24 + kt) * 64 + lane]);
          hz = MFMA(a, w, hz);
        }
#pragma unroll
        for (int r = 0; r < 4; ++r)
          HZp[(lrow * 4 + r) * HZS + nt * 16 + lcol] = f2bf(fmaxf(hz[r], 0.f));
      }
    }
    __syncthreads();

    // phase 5: mean/log_var heads (W5,W6 inf; W8,W9 pri), K=64, 1 tile/wave
    {
      int m = wave >> 2, q = wave & 3;
      const short8* W = (m == 0) ? p.W5f : (m == 1) ? p.W6f : (m == 2) ? p.W8f : p.W9f;
      const float* bb = (m == 0) ? p.b5 : (m == 1) ? p.b6 : (m == 2) ? p.b8 : p.b9;
      const short* As = (m < 2) ? HZi : HZp;
      float b = bb[q * 16 + lcol];
      f32x4 o = (f32x4){b, b, b, b};
#pragma unroll
      for (int kt = 0; kt < 2; ++kt) {
        short8 a = *(const short8*)&As[lcol * HZS + kt * 32 + lrow * 8];
        short8 w = __builtin_nontemporal_load(&W[(q * 2 + kt) * 64 + lane]);
        o = MFMA(a, w, o);
      }
#pragma unroll
      for (int r = 0; r < 4; ++r) {
        int row = lrow * 4 + r;
        int col = q * 16 + lcol;
        float v = fmaxf(o[r], 0.f);
        size_t gb = (size_t)(rowbase + row) * 1024 + t * 64;
        if (m == 0) {
          Mi[row * 64 + col] = v;
          __builtin_nontemporal_store(v, &p.out[O1 + gb + col]);
        } else if (m == 1) {
          Li[row * 64 + col] = v;
          __builtin_nontemporal_store(v, &p.out[O2 + gb + col]);
        } else if (m == 2) {
          Mp[row * 64 + col] = v;
        } else {
          Lp[row * 64 + col] = v;
        }
      }
    }
    __syncthreads();

    // phase 6: z sampling + output + state shuffles
    {
      int e = tid;  // 1024 threads, 1024 elements
      int row = e >> 6, col = e & 63;
      int b = rowbase + row;
      float ei = __builtin_nontemporal_load(&p.eps_inf[((size_t)t * Bt + b) * 64 + col]);
      float ep = __builtin_nontemporal_load(&p.eps_pri[((size_t)t * Bt + b) * 64 + col]);
      float zi = Mi[e] + ei * sqrtf(__expf(Li[e]));
      float zp = Mp[e] + ep * sqrtf(__expf(Lp[e]));
      __builtin_nontemporal_store(zi, &p.out[O3 + ((size_t)(t * 2 + 0) * Bt + b) * 64 + col]);
      __builtin_nontemporal_store(zp, &p.out[O3 + ((size_t)(t * 2 + 1) * Bt + b) * 64 + col]);
      A1[row * A1S + col] = f2bf(zi);   // z state for next step
    }
    for (int i = tid; i < 16 * 256; i += 1024) {
      int r = i >> 8, c = i & 255;
      short v = A4[r * A4S + 768 + c];  // y_cur
      A1[r * A1S + 64 + c] = v;         // -> A1.y_prev
      A4[r * A4S + 512 + c] = v;        // -> A4.y_prev
    }
    __syncthreads();
  }
}

extern "C" void kernel_launch(void* const* d_in, const int* in_sizes, int n_in,
                              void* d_out, int out_size, void* d_ws, size_t ws_size,
                              hipStream_t stream) {
  const float* h_i     = (const float*)d_in[0];
  const float* eps_inf = (const float*)d_in[1];
  const float* eps_pri = (const float*)d_in[2];
  const float* Wx      = (const float*)d_in[3];
  const float* Wh      = (const float*)d_in[4];
  const float* b_lstm  = (const float*)d_in[5];
  const float* W1 = (const float*)d_in[6];  const float* b1 = (const float*)d_in[7];
  const float* W2 = (const float*)d_in[8];  const float* b2 = (const float*)d_in[9];
  const float* W3 = (const float*)d_in[10]; const float* b3 = (const float*)d_in[11];
  const float* W4 = (const float*)d_in[12]; const float* b4 = (const float*)d_in[13];
  const float* W5 = (const float*)d_in[14]; const float* b5 = (const float*)d_in[15];
  const float* W6 = (const float*)d_in[16]; const float* b6 = (const float*)d_in[17];
  const float* W7 = (const float*)d_in[18]; const float* b7 = (const float*)d_in[19];
  const float* W8 = (const float*)d_in[20]; const float* b8 = (const float*)d_in[21];
  const float* W9 = (const float*)d_in[22]; const float* b9 = (const float*)d_in[23];
  short8* ws = (short8*)d_ws;
  const float* nil = nullptr;

  auto cv = [&](const float* s0, int k0, const float* s1, int k1,
                const float* s2, int k2, int N, int off, int KT, int NT) {
    int total = NT * KT * 64;
    conv_frag<<<(total + 255) / 256, 256, 0, stream>>>(s0, k0, s1, k1, s2, k2,
                                                       N, ws + off, KT, total);
  };
  // gates dyn: [z (Wx rows 0:64) | y_prev (Wx rows 576:832) | h (Wh)]
  cv(Wx, 64, Wx + 576 * 2048, 256, Wh, 512, 2048, OFF_WG, 26, 128);
  cv(Wx + 64 * 2048, 512, nil, 0, nil, 0, 2048, OFF_WPH, 16, 128);
  cv(W1, 512, nil, 0, nil, 0, 256, OFF_W1, 16, 16);
  cv(W2, 256, nil, 0, nil, 0, 256, OFF_W2, 8, 16);
  cv(W3, 256, nil, 0, nil, 0, 256, OFF_W3, 8, 16);
  // W4 dyn: [s (rows 512:1024) | y_prev (rows 1280:1536) | y_cur (rows 1024:1280)]
  cv(W4 + 512 * 64, 512, W4 + 1280 * 64, 256, W4 + 1024 * 64, 256, 64, OFF_W4D, 32, 4);
  cv(W4, 512, nil, 0, nil, 0, 64, OFF_W4H, 16, 4);
  // W7 dyn: [s (rows 512:1024) | y_prev (rows 1024:1280)]
  cv(W7 + 512 * 64, 512, W7 + 1024 * 64, 256, nil, 0, 64, OFF_W7D, 24, 4);
  cv(W7, 512, nil, 0, nil, 0, 64, OFF_W7H, 16, 4);
  cv(W5, 64, nil, 0, nil, 0, 64, OFF_W5, 2, 4);
  cv(W6, 64, nil, 0, nil, 0, 64, OFF_W6, 2, 4);
  cv(W8, 64, nil, 0, nil, 0, 64, OFF_W8, 2, 4);
  cv(W9, 64, nil, 0, nil, 0, 64, OFF_W9, 2, 4);

  Params P{h_i, eps_inf, eps_pri, b_lstm,
           b1, b2, b3, b4, b5, b6, b7, b8, b9,
           ws + OFF_WG, ws + OFF_WPH, ws + OFF_W1, ws + OFF_W2, ws + OFF_W3,
           ws + OFF_W4D, ws + OFF_W4H, ws + OFF_W7D, ws + OFF_W7H,
           ws + OFF_W5, ws + OFF_W6, ws + OFF_W8, ws + OFF_W9,
           (float*)d_out};
  vrnn_kernel<<<256, 1024, 0, stream>>>(P);
}